// Round 6
// baseline (314.993 us; speedup 1.0000x reference)
//
#include <hip/hip_runtime.h>
#include <math.h>

// N=50000, E=400000, U=32, R=32. All fp32 inputs; edge_index int32.
//
// R11 (270.7 us): grid 768->1536 on edge: occupancy UNCHANGED (25%), dur
//   unchanged -> occupancy theory wrong. VGPR_Count=84 vs static demand
//   ~120 (aw[18]=72 + ~50 live state) => compiler spilled the weight frags;
//   every tile re-fetches ~18KB/wave from scratch/L2 on the critical path.
//   Explains MfmaUtil 4%, VALU 30%, nothing saturated, grid-size null.
// R12 (this round), edge kernel only:
//   - Stage all 18 weight frags (18KB) + biases in LDS once per block.
//   - Keep only W1/W2 frags (24 VGPR) resident; W3 frags read JIT via
//     ds_read_b128 in the layer-3 loop (12 reads/tile, ~12cy each).
//   - __launch_bounds__(256,4): VGPR cap 128, demand ~90 -> no spill.
//   Node/CSR/prep kernels and all layouts unchanged.

typedef _Float16 h2    __attribute__((ext_vector_type(2)));
typedef __fp16   p2    __attribute__((ext_vector_type(2)));
typedef _Float16 f16x8 __attribute__((ext_vector_type(8)));
typedef float    f32x4 __attribute__((ext_vector_type(4)));

union U8 { unsigned u[4]; uint4 q; f16x8 v; };
union C4 { float4 f; f32x4 v; };

__device__ __forceinline__ h2 as_h2(unsigned u){ union{unsigned x; h2 h;} c; c.x=u; return c.h; }
__device__ __forceinline__ unsigned h2bits(h2 h){ union{h2 h; unsigned x;} c; c.h=h; return c.x; }

__device__ __forceinline__ float dot2(h2 a, h2 b, float c){
#if __has_builtin(__builtin_amdgcn_fdot2)
    return __builtin_amdgcn_fdot2(a, b, c, false);
#else
    return c + (float)a.x*(float)b.x + (float)a.y*(float)b.y;
#endif
}

__device__ __forceinline__ h2 pk(float a, float b){
#if __has_builtin(__builtin_amdgcn_cvt_pkrtz)
    union { p2 p; h2 h; } c;
    c.p = __builtin_amdgcn_cvt_pkrtz(a, b);
    return c.h;
#else
    h2 r; r.x=(_Float16)a; r.y=(_Float16)b; return r;
#endif
}

// round-to-nearest f16 pack (for node path precision)
__device__ __forceinline__ unsigned pk_rtn(float a, float b){
    union { h2 h; unsigned x; } c;
    c.h.x = (_Float16)a; c.h.y = (_Float16)b;
    return c.x;
}

__device__ __forceinline__ float fast_silu(float x){
    return x * __builtin_amdgcn_rcpf(1.0f + __expf(-x));
}

// ---- prep ------------------------------------------------------------------
// whn  : node tensor weights f16: uint4[2 call][16 kp][32 u], word c<3 =
//        h2{Wt[3*call+c][u][2kp], Wt[3*call+c][u][2kp+1]}, word3 = 0
// ball : [b1(32) | b2(64) | b3 permuted to o=c*32+u order (96)]  f32
// wfrag: 18 MFMA A-fragments x 64 lanes x 4 u32 (packed f16 pairs)
__global__ __launch_bounds__(256) void prep_kernel(
    const float* __restrict__ Wt,
    const float* __restrict__ W1, const float* __restrict__ b1,
    const float* __restrict__ W2, const float* __restrict__ b2,
    const float* __restrict__ W3, const float* __restrict__ b3,
    unsigned* __restrict__ whn, float* __restrict__ ball, unsigned* __restrict__ wfrag)
{
    int i = blockIdx.x * 256 + threadIdx.x;
    if (i < 4096) {
        int call = i >> 11, r = i & 2047, kp = r >> 7, rem = r & 127;
        int u = rem >> 2, c = rem & 3;
        unsigned val = 0;
        if (c < 3) {
            const float* W = Wt + (size_t)(3*call + c)*1024 + u*32 + 2*kp;
            val = pk_rtn(W[0], W[1]);
        }
        whn[i] = val;
    }
    if (i < 192) {
        float v;
        if (i < 32)      v = b1[i];
        else if (i < 96) v = b2[i-32];
        else {
            int o = i - 96;                       // output slot o = c*32+u
            v = b3[(o & 31)*3 + (o >> 5)];        // original row m = u*3+c
        }
        ball[i] = v;
    }
    if (i < 4608) {
        int f = i >> 8, l = (i >> 2) & 63, wi = i & 3;
        int row = l & 15, qq = l >> 4;
        int kb = 8*qq + 2*wi;
        float v0, v1;
        if (f < 2) {
            int m = 16*f + row;
            v0 = W1[m*32 + kb]; v1 = W1[m*32 + kb + 1];
        } else if (f < 6) {
            int m = 16*(f-2) + row;
            v0 = W2[m*32 + kb]; v1 = W2[m*32 + kb + 1];
        } else {
            int idx = f - 6, mt = idx >> 1, kh = idx & 1;
            int mp = 16*mt + row;
            int om = (mp & 31)*3 + (mp >> 5);
            int k  = 32*kh + kb;
            v0 = W3[om*64 + k]; v1 = W3[om*64 + k + 1];
        }
        wfrag[i] = pk_rtn(v0, v1);
    }
}

// ---- CSR build ---------------------------------------------------------------
__global__ __launch_bounds__(256) void hist_kernel(
    const int* __restrict__ edge_index, int* __restrict__ cnt, int nE)
{
    int e = blockIdx.x * 256 + threadIdx.x;
    if (e < nE) atomicAdd(&cnt[edge_index[nE + e]], 1);
}

__global__ __launch_bounds__(1024) void scanA_kernel(
    const int* __restrict__ cnt, int* __restrict__ rowptr,
    int* __restrict__ csum, int nN)
{
    __shared__ int wsum[16];
    __shared__ int wpre[16];
    int tid = threadIdx.x, lane = tid & 63, wid = tid >> 6;
    int i = blockIdx.x * 1024 + tid;
    int orig = (i < nN) ? cnt[i] : 0;
    int v = orig;
    #pragma unroll
    for (int d = 1; d < 64; d <<= 1) { int o = __shfl_up(v, d); if (lane >= d) v += o; }
    if (lane == 63) wsum[wid] = v;
    __syncthreads();
    if (wid == 0) {
        int s = (lane < 16) ? wsum[lane] : 0;
        #pragma unroll
        for (int d = 1; d < 16; d <<= 1) { int o = __shfl_up(s, d); if (lane >= d) s += o; }
        if (lane < 16) wpre[lane] = s;
    }
    __syncthreads();
    int badd = wid ? wpre[wid - 1] : 0;
    if (i < nN) rowptr[i] = badd + v - orig;
    if (tid == 1023) csum[blockIdx.x] = badd + v;
}

__global__ __launch_bounds__(64) void scanB_kernel(
    int* __restrict__ csum, int* __restrict__ rowptr, int nChunks, int nN)
{
    int lane = threadIdx.x;
    int orig = (lane < nChunks) ? csum[lane] : 0;
    int s = orig;
    #pragma unroll
    for (int d = 1; d < 64; d <<= 1) { int o = __shfl_up(s, d); if (lane >= d) s += o; }
    if (lane < nChunks) csum[lane] = s - orig;
    if (lane == 63) rowptr[nN] = s;
}

__global__ __launch_bounds__(1024) void scanC_kernel(
    const int* __restrict__ csum, int* __restrict__ rowptr, int nN)
{
    int i = blockIdx.x * 1024 + threadIdx.x;
    if (i < nN) rowptr[i] += csum[i >> 10];
}

// ---- edge: MFMA MLP, LDS-resident weights -----------------------------------
// One wave = 16 edges. Transposed: D[m][e] = sum_k W[m][k] act[e][k] + b[m].
// D layout (m89-verified): col(e)=lane&15, row(m)=(lane>>4)*4+r.
// A/B layout: row/col = lane&15, k = 8*(lane>>4)+j (contiguous k, b128-style).
__global__ __launch_bounds__(256, 4) void edge_mfma_kernel(
    const float* __restrict__ edge_attr,
    const float* __restrict__ edge_weight,
    const int* __restrict__ edge_index,
    const int* __restrict__ rowptr,
    int* __restrict__ cursor,
    const unsigned* __restrict__ wfrag,
    const float* __restrict__ ball,
    float* __restrict__ buf, int nE)
{
    __shared__ __align__(16) uint4 swf[1152];   // 18KB: 18 frags x 64 lanes
    __shared__ __align__(16) float sball[192];
    int tid = threadIdx.x;
    {
        const uint4* g4 = reinterpret_cast<const uint4*>(wfrag);
        for (int i = tid; i < 1152; i += 256) swf[i] = g4[i];
        if (tid < 192) sball[tid] = ball[tid];
    }
    __syncthreads();

    int lane = tid & 63;
    int wid  = (blockIdx.x << 2) + (tid >> 6);
    int nW   = gridDim.x << 2;
    int T    = (nE + 15) >> 4;

    // W1/W2 fragments resident (24 VGPRs) — head of the dependent chain.
    U8 aw[6];
    #pragma unroll
    for (int f = 0; f < 6; ++f) aw[f].q = swf[f*64 + lane];
    const uint4* w3p = &swf[6*64 + lane];       // W3 frag f at w3p[f*64]

    int q = lane >> 4, ecol = lane & 15;
    bool hiq = lane >= 32;
    int sl = ecol + ((lane & 16) << 1);
    int sh = sl + 16;

    unsigned* bufu = reinterpret_cast<unsigned*>(buf);

    // prefetch first tile (incl. dst node and its rowptr)
    int tile = wid;
    float4 pA = make_float4(0,0,0,0), pB = pA; float pew = 0.f;
    int pd = 0, prp = 0;
    if (tile < T) {
        int e = tile*16 + ecol; if (e >= nE) e = nE - 1;
        const float* eap = edge_attr + (size_t)e*32 + q*8;
        pA = *reinterpret_cast<const float4*>(eap);
        pB = *reinterpret_cast<const float4*>(eap + 4);
        pew = edge_weight[e];
        if (lane < 16) { pd = edge_index[nE + e]; prp = rowptr[pd]; }
    }

    for (; tile < T; tile += nW) {
        float4 cA = pA, cB = pB; float ew = pew; int d = pd, rp = prp;
        bool ev = (tile*16 + ecol) < nE;

        // slot atomic first: ~300cy L2 latency overlaps all 3 MFMA layers.
        int slot = 0;
        if (lane < 16 && ev) slot = rp + atomicAdd(&cursor[d], 1);
        int slotAll = __shfl(slot, ecol);

        // prefetch next tile
        int nt = tile + nW;
        if (nt < T) {
            int e = nt*16 + ecol; if (e >= nE) e = nE - 1;
            const float* eap = edge_attr + (size_t)e*32 + q*8;
            pA = *reinterpret_cast<const float4*>(eap);
            pB = *reinterpret_cast<const float4*>(eap + 4);
            pew = edge_weight[e];
            if (lane < 16) { pd = edge_index[nE + e]; prp = rowptr[pd]; }
        }

        // B_ea: col=edge, k=8q+j
        U8 bea;
        bea.u[0] = h2bits(pk(cA.x, cA.y));
        bea.u[1] = h2bits(pk(cA.z, cA.w));
        bea.u[2] = h2bits(pk(cB.x, cB.y));
        bea.u[3] = h2bits(pk(cB.z, cB.w));

        // ---- layer 1: h1T(32xE) = silu(W1 @ eaT + b1) ----
        unsigned w1w[4];
        #pragma unroll
        for (int t = 0; t < 2; ++t) {
            C4 c; c.f = *reinterpret_cast<const float4*>(&sball[16*t + 4*q]);
            f32x4 acc = c.v;
            acc = __builtin_amdgcn_mfma_f32_16x16x32_f16(aw[t].v, bea.v, acc, 0, 0, 0);
            w1w[2*t]   = h2bits(pk(fast_silu(acc[0]), fast_silu(acc[1])));
            w1w[2*t+1] = h2bits(pk(fast_silu(acc[2]), fast_silu(acc[3])));
        }

        // transpose D->B
        U8 bh1;
        {
            unsigned t0 = (unsigned)__shfl((int)w1w[0], sl), t2 = (unsigned)__shfl((int)w1w[2], sl);
            bh1.u[0] = hiq ? t2 : t0;
            unsigned t1 = (unsigned)__shfl((int)w1w[1], sl), t3 = (unsigned)__shfl((int)w1w[3], sl);
            bh1.u[1] = hiq ? t3 : t1;
            t0 = (unsigned)__shfl((int)w1w[0], sh); t2 = (unsigned)__shfl((int)w1w[2], sh);
            bh1.u[2] = hiq ? t2 : t0;
            t1 = (unsigned)__shfl((int)w1w[1], sh); t3 = (unsigned)__shfl((int)w1w[3], sh);
            bh1.u[3] = hiq ? t3 : t1;
        }

        // ---- layer 2: h2T(64xE) = silu(W2 @ h1T + b2) ----
        unsigned w2w[8];
        #pragma unroll
        for (int t = 0; t < 4; ++t) {
            C4 c; c.f = *reinterpret_cast<const float4*>(&sball[32 + 16*t + 4*q]);
            f32x4 acc = c.v;
            acc = __builtin_amdgcn_mfma_f32_16x16x32_f16(aw[2+t].v, bh1.v, acc, 0, 0, 0);
            w2w[2*t]   = h2bits(pk(fast_silu(acc[0]), fast_silu(acc[1])));
            w2w[2*t+1] = h2bits(pk(fast_silu(acc[2]), fast_silu(acc[3])));
        }

        // transpose -> two B-frags (k-halves of 64)
        U8 b3f[2];
        #pragma unroll
        for (int h = 0; h < 2; ++h) {
            unsigned ta = (unsigned)__shfl((int)w2w[4*h],   sl), tb = (unsigned)__shfl((int)w2w[4*h+2], sl);
            b3f[h].u[0] = hiq ? tb : ta;
            unsigned tc = (unsigned)__shfl((int)w2w[4*h+1], sl), td = (unsigned)__shfl((int)w2w[4*h+3], sl);
            b3f[h].u[1] = hiq ? td : tc;
            ta = (unsigned)__shfl((int)w2w[4*h],   sh); tb = (unsigned)__shfl((int)w2w[4*h+2], sh);
            b3f[h].u[2] = hiq ? tb : ta;
            tc = (unsigned)__shfl((int)w2w[4*h+1], sh); td = (unsigned)__shfl((int)w2w[4*h+3], sh);
            b3f[h].u[3] = hiq ? td : tc;
        }

        float Cc = (ew < 5.0f) ? 0.5f * (__cosf(ew * 0.6283185307179586f) + 1.0f) : 0.0f;

        // ---- layer 3: out(96xE) = silu(W3p @ h2T + b3p) * Cc ----
        // W3 fragments read JIT from LDS (ds_read_b128), not register-resident.
        size_t sb = (size_t)slotAll * 48 + 2*q;
        #pragma unroll
        for (int mt = 0; mt < 6; ++mt) {
            U8 wa, wb;
            wa.q = w3p[(2*mt)*64];
            wb.q = w3p[(2*mt+1)*64];
            C4 c; c.f = *reinterpret_cast<const float4*>(&sball[96 + 16*mt + 4*q]);
            f32x4 acc = c.v;
            acc = __builtin_amdgcn_mfma_f32_16x16x32_f16(wa.v, b3f[0].v, acc, 0, 0, 0);
            acc = __builtin_amdgcn_mfma_f32_16x16x32_f16(wb.v, b3f[1].v, acc, 0, 0, 0);
            unsigned p0 = h2bits(pk(fast_silu(acc[0])*Cc, fast_silu(acc[1])*Cc));
            unsigned p1 = h2bits(pk(fast_silu(acc[2])*Cc, fast_silu(acc[3])*Cc));
            if (ev) *reinterpret_cast<uint2*>(bufu + sb + 8*mt) = make_uint2(p0, p1);
        }
    }
}

// ---- node kernel v2: f16 dot2 comp_linear (unchanged from R10) --------------
__device__ __forceinline__ void comp_linear2(
    const unsigned* __restrict__ sW, const unsigned* __restrict__ cbu,
    int u, int call, float& Il, float* a, float* s)
{
    const uint4* w4 = reinterpret_cast<const uint4*>(sW) + call*512 + u;
    const uint4* c4 = reinterpret_cast<const uint4*>(cbu);
    Il = 0.f; a[0]=a[1]=a[2]=0.f;
    s[0]=s[1]=s[2]=s[3]=s[4]=s[5]=0.f;
    #pragma unroll
    for (int kp2 = 0; kp2 < 8; ++kp2) {
        uint4 r0 = c4[kp2*5+0], r1 = c4[kp2*5+1], r2 = c4[kp2*5+2],
              r3 = c4[kp2*5+3], r4 = c4[kp2*5+4];
        uint4 w0 = w4[(2*kp2)*32], w1 = w4[(2*kp2+1)*32];
        Il   = dot2(as_h2(r0.x), as_h2(w0.x), Il);
        a[0] = dot2(as_h2(r0.y), as_h2(w0.y), a[0]);
        a[1] = dot2(as_h2(r0.z), as_h2(w0.y), a[1]);
        a[2] = dot2(as_h2(r0.w), as_h2(w0.y), a[2]);
        s[0] = dot2(as_h2(r1.x), as_h2(w0.z), s[0]);
        s[1] = dot2(as_h2(r1.y), as_h2(w0.z), s[1]);
        s[2] = dot2(as_h2(r1.z), as_h2(w0.z), s[2]);
        s[3] = dot2(as_h2(r1.w), as_h2(w0.z), s[3]);
        s[4] = dot2(as_h2(r2.x), as_h2(w0.z), s[4]);
        s[5] = dot2(as_h2(r2.y), as_h2(w0.z), s[5]);
        Il   = dot2(as_h2(r2.z), as_h2(w1.x), Il);
        a[0] = dot2(as_h2(r2.w), as_h2(w1.y), a[0]);
        a[1] = dot2(as_h2(r3.x), as_h2(w1.y), a[1]);
        a[2] = dot2(as_h2(r3.y), as_h2(w1.y), a[2]);
        s[0] = dot2(as_h2(r3.z), as_h2(w1.z), s[0]);
        s[1] = dot2(as_h2(r3.w), as_h2(w1.z), s[1]);
        s[2] = dot2(as_h2(r4.x), as_h2(w1.z), s[2]);
        s[3] = dot2(as_h2(r4.y), as_h2(w1.z), s[3]);
        s[4] = dot2(as_h2(r4.z), as_h2(w1.z), s[4]);
        s[5] = dot2(as_h2(r4.w), as_h2(w1.z), s[5]);
    }
}

__device__ __forceinline__ void compose(float Il, const float* a, const float* s, float (&T)[3][3])
{
    T[0][0] =  Il  + s[0]; T[0][1] =  a[0] + s[1]; T[0][2] =  a[1] + s[2];
    T[1][0] = -a[0] + s[1]; T[1][1] =  Il  + s[3]; T[1][2] =  a[2] + s[4];
    T[2][0] = -a[1] + s[2]; T[2][1] = -a[2] + s[4]; T[2][2] =  Il  + s[5];
}

__global__ __launch_bounds__(256) void node_kernel(
    const float* __restrict__ X,
    const unsigned* __restrict__ whn,
    const int* __restrict__ rowptr,
    const float* __restrict__ buf,
    float* __restrict__ out, int nN)
{
    __shared__ __align__(16) unsigned sW[4096];     // 16KB f16 weights
    __shared__ __align__(16) _Float16 sC[8][320];   // 5KB cb (f16)

    int tid = threadIdx.x;
    {
        const uint4* g4 = reinterpret_cast<const uint4*>(whn);
        uint4* s4 = reinterpret_cast<uint4*>(sW);
        #pragma unroll
        for (int i = 0; i < 4; ++i) s4[tid + 256*i] = g4[tid + 256*i];
    }

    int ln = tid >> 5, u = tid & 31;
    int n  = blockIdx.x * 8 + ln;
    if (n >= nN) n = nN - 1;
    const unsigned* cbu = reinterpret_cast<const unsigned*>(&sC[ln][0]);
    _Float16* cw = &sC[ln][(u >> 1)*20 + (u & 1)];

    int r0 = rowptr[n], r1 = rowptr[n + 1];
    float sIv = 0.f, sAv = 0.f, sSv = 0.f;
    const _Float16* bp = reinterpret_cast<const _Float16*>(buf) + (size_t)r0 * 96 + u;
    for (int i = r0; i < r1; ++i, bp += 96) {
        sIv += (float)bp[0];    // I plane
        sAv += (float)bp[32];   // A plane
        sSv += (float)bp[64];   // S plane
    }

    const float* xp = X + (size_t)n * 288 + u;
    float x[3][3];
    float nrm = 1.0f;
    #pragma unroll
    for (int i = 0; i < 3; ++i)
        #pragma unroll
        for (int j = 0; j < 3; ++j) {
            float v = xp[(i*3 + j) * 32];
            x[i][j] = v; nrm += v * v;
        }
    float inv = 1.0f / nrm;
    #pragma unroll
    for (int i = 0; i < 3; ++i)
        #pragma unroll
        for (int j = 0; j < 3; ++j) x[i][j] *= inv;

    float tI = (x[0][0] + x[1][1] + x[2][2]) * (1.0f/3.0f);
    cw[0]  = (_Float16)tI;
    cw[2]  = (_Float16)(0.5f * (x[0][1] - x[1][0]));
    cw[4]  = (_Float16)(0.5f * (x[0][2] - x[2][0]));
    cw[6]  = (_Float16)(0.5f * (x[1][2] - x[2][1]));
    cw[8]  = (_Float16)(x[0][0] - tI);
    cw[10] = (_Float16)(0.5f * (x[0][1] + x[1][0]));
    cw[12] = (_Float16)(0.5f * (x[0][2] + x[2][0]));
    cw[14] = (_Float16)(x[1][1] - tI);
    cw[16] = (_Float16)(0.5f * (x[1][2] + x[2][1]));
    cw[18] = (_Float16)(x[2][2] - tI);
    __syncthreads();   // sW staging + cb publish

    float Il, a[3], s[6];
    comp_linear2(sW, cbu, u, 0, Il, a, s);

    float Ym[3][3], Gm[3][3];
    compose(Il, a, s, Ym);
    float am[3] = {a[0]*sAv, a[1]*sAv, a[2]*sAv};
    float sm[6] = {s[0]*sSv, s[1]*sSv, s[2]*sSv, s[3]*sSv, s[4]*sSv, s[5]*sSv};
    compose(Il * sIv, am, sm, Gm);

    float M[3][3]; float np1 = 1.0f;
    #pragma unroll
    for (int i = 0; i < 3; ++i)
        #pragma unroll
        for (int l = 0; l < 3; ++l) {
            float v = 0.f;
            #pragma unroll
            for (int j = 0; j < 3; ++j) v += Ym[i][j]*Gm[j][l] + Gm[i][j]*Ym[j][l];
            M[i][l] = v; np1 += v * v;
        }
    float rinv = 1.0f / np1;
    float tI2 = (M[0][0] + M[1][1] + M[2][2]) * (1.0f/3.0f);

    __builtin_amdgcn_wave_barrier();
    cw[0]  = (_Float16)(tI2 * rinv);
    cw[2]  = (_Float16)(0.5f * (M[0][1] - M[1][0]) * rinv);
    cw[4]  = (_Float16)(0.5f * (M[0][2] - M[2][0]) * rinv);
    cw[6]  = (_Float16)(0.5f * (M[1][2] - M[2][1]) * rinv);
    cw[8]  = (_Float16)((M[0][0] - tI2) * rinv);
    cw[10] = (_Float16)(0.5f * (M[0][1] + M[1][0]) * rinv);
    cw[12] = (_Float16)(0.5f * (M[0][2] + M[2][0]) * rinv);
    cw[14] = (_Float16)((M[1][1] - tI2) * rinv);
    cw[16] = (_Float16)(0.5f * (M[1][2] + M[2][1]) * rinv);
    cw[18] = (_Float16)((M[2][2] - tI2) * rinv);
    __builtin_amdgcn_wave_barrier();

    comp_linear2(sW, cbu, u, 1, Il, a, s);
    float D[3][3];
    compose(Il, a, s, D);

    float* op = out + (size_t)n * 288 + u;
    #pragma unroll
    for (int i = 0; i < 3; ++i)
        #pragma unroll
        for (int l = 0; l < 3; ++l) {
            float v = x[i][l] + D[i][l];
            #pragma unroll
            for (int j = 0; j < 3; ++j) v += D[i][j] * D[j][l];
            op[(i*3 + l) * 32] = v;
        }
}

extern "C" void kernel_launch(void* const* d_in, const int* in_sizes, int n_in,
                              void* d_out, int out_size, void* d_ws, size_t ws_size,
                              hipStream_t stream) {
    const float* X   = (const float*)d_in[0];
    const int*   ei  = (const int*)d_in[1];
    const float* ew  = (const float*)d_in[2];
    const float* ea  = (const float*)d_in[3];
    const float* W1  = (const float*)d_in[4];
    const float* b1  = (const float*)d_in[5];
    const float* W2  = (const float*)d_in[6];
    const float* b2  = (const float*)d_in[7];
    const float* W3  = (const float*)d_in[8];
    const float* b3  = (const float*)d_in[9];
    const float* Wt  = (const float*)d_in[10];

    int nE = in_sizes[2];          // 400000
    int nN = in_sizes[0] / 288;    // 50000
    int nChunks = (nN + 1023) / 1024;

    float* ws       = (float*)d_ws;
    unsigned* whn   = (unsigned*)ws;             // 4096 u32 (16KB), region padded to 8192 f
    float* ball     = ws + 8192;                 // 192 floats (pad to 256)
    unsigned* wfrag = (unsigned*)(ws + 8448);    // 4608 u32 MFMA weight frags
    float* buf      = ws + 8448 + 4608;          // nE*48 floats (= nE*96 halves)
    size_t buf_f    = (size_t)nE * 48;
    int* ib     = (int*)(buf + buf_f);
    int* cntA   = ib;                 // nN
    int* cursor = ib + nN;            // nN
    int* rowptr = ib + 2 * nN;        // nN+1
    int* csum   = ib + 3 * nN + 1;    // nChunks (<=64)

    prep_kernel<<<36, 256, 0, stream>>>(Wt, W1, b1, W2, b2, W3, b3, whn, ball, wfrag);
    (void)hipMemsetAsync(cntA, 0, (size_t)2 * nN * sizeof(int), stream);
    hist_kernel<<<(nE + 255) / 256, 256, 0, stream>>>(ei, cntA, nE);
    scanA_kernel<<<nChunks, 1024, 0, stream>>>(cntA, rowptr, csum, nN);
    scanB_kernel<<<1, 64, 0, stream>>>(csum, rowptr, nChunks, nN);
    scanC_kernel<<<nChunks, 1024, 0, stream>>>(csum, rowptr, nN);
    edge_mfma_kernel<<<1536, 256, 0, stream>>>(
        ea, ew, ei, rowptr, cursor, wfrag, ball, buf, nE);
    node_kernel<<<(nN + 7) / 8, 256, 0, stream>>>(
        X, whn, rowptr, buf, (float*)d_out, nN);
}

// Round 7
// 269.461 us; speedup vs baseline: 1.1690x; 1.1690x over previous
//
#include <hip/hip_runtime.h>
#include <math.h>

// N=50000, E=400000, U=32, R=32. All fp32 inputs; edge_index int32.
//
// R11 (271 us, best): edge VGPR 84, no scratch traffic -> compiler was
//   rematerializing the 18 weight frags from GLOBAL per tile (not scratch-
//   spilling as theorized). Also hidden: 12 loop-invariant bias float4
//   reads = 48 VGPR if hoisted.
// R12 (315 us, REGRESSION): launch_bounds(256,4) -> backend squeezed to
//   64 VGPR (8 waves/SIMD feasible w/ 19.5KB LDS) -> true scratch spills:
//   FETCH 28->105MB, WRITE 88->139MB, VALU 16%.
// R13 (this round):
//   Edge: LDS-resident weights+biases, ALL reads JIT ds_read with LICM
//     defeated via opaque zero index (asm "+v"(ob) per iteration); plain
//     launch_bounds(256). Demand ~70 VGPR -> nothing to spill; weight
//     reload cost 30x ds_read_b128 (~12cy) vs 18x global (~200cy).
//   Plumbing: 9 -> 6 launches (memset folded into prep; scanB folded into
//     scanC via 64-lane shuffle reduce of chunk sums).

typedef _Float16 h2    __attribute__((ext_vector_type(2)));
typedef __fp16   p2    __attribute__((ext_vector_type(2)));
typedef _Float16 f16x8 __attribute__((ext_vector_type(8)));
typedef float    f32x4 __attribute__((ext_vector_type(4)));

union U8 { unsigned u[4]; uint4 q; f16x8 v; };
union C4 { float4 f; f32x4 v; };

__device__ __forceinline__ h2 as_h2(unsigned u){ union{unsigned x; h2 h;} c; c.x=u; return c.h; }
__device__ __forceinline__ unsigned h2bits(h2 h){ union{h2 h; unsigned x;} c; c.h=h; return c.x; }

__device__ __forceinline__ float dot2(h2 a, h2 b, float c){
#if __has_builtin(__builtin_amdgcn_fdot2)
    return __builtin_amdgcn_fdot2(a, b, c, false);
#else
    return c + (float)a.x*(float)b.x + (float)a.y*(float)b.y;
#endif
}

__device__ __forceinline__ h2 pk(float a, float b){
#if __has_builtin(__builtin_amdgcn_cvt_pkrtz)
    union { p2 p; h2 h; } c;
    c.p = __builtin_amdgcn_cvt_pkrtz(a, b);
    return c.h;
#else
    h2 r; r.x=(_Float16)a; r.y=(_Float16)b; return r;
#endif
}

// round-to-nearest f16 pack (for node path precision)
__device__ __forceinline__ unsigned pk_rtn(float a, float b){
    union { h2 h; unsigned x; } c;
    c.h.x = (_Float16)a; c.h.y = (_Float16)b;
    return c.x;
}

__device__ __forceinline__ float fast_silu(float x){
    return x * __builtin_amdgcn_rcpf(1.0f + __expf(-x));
}

// ---- prep (+ zero cnt/cursor) ----------------------------------------------
// whn  : node tensor weights f16: uint4[2 call][16 kp][32 u]
// ball : [b1(32) | b2(64) | b3 permuted to o=c*32+u order (96)]  f32
// wfrag: 18 MFMA A-fragments x 64 lanes x 4 u32 (packed f16 pairs)
__global__ __launch_bounds__(256) void prep_kernel(
    const float* __restrict__ Wt,
    const float* __restrict__ W1, const float* __restrict__ b1,
    const float* __restrict__ W2, const float* __restrict__ b2,
    const float* __restrict__ W3, const float* __restrict__ b3,
    unsigned* __restrict__ whn, float* __restrict__ ball, unsigned* __restrict__ wfrag,
    int* __restrict__ cz, int nZ)
{
    int i = blockIdx.x * 256 + threadIdx.x;
    if (i < nZ) cz[i] = 0;                        // cnt + cursor zeroing
    if (i < 4096) {
        int call = i >> 11, r = i & 2047, kp = r >> 7, rem = r & 127;
        int u = rem >> 2, c = rem & 3;
        unsigned val = 0;
        if (c < 3) {
            const float* W = Wt + (size_t)(3*call + c)*1024 + u*32 + 2*kp;
            val = pk_rtn(W[0], W[1]);
        }
        whn[i] = val;
    }
    if (i < 192) {
        float v;
        if (i < 32)      v = b1[i];
        else if (i < 96) v = b2[i-32];
        else {
            int o = i - 96;                       // output slot o = c*32+u
            v = b3[(o & 31)*3 + (o >> 5)];        // original row m = u*3+c
        }
        ball[i] = v;
    }
    if (i < 4608) {
        int f = i >> 8, l = (i >> 2) & 63, wi = i & 3;
        int row = l & 15, qq = l >> 4;
        int kb = 8*qq + 2*wi;
        float v0, v1;
        if (f < 2) {
            int m = 16*f + row;
            v0 = W1[m*32 + kb]; v1 = W1[m*32 + kb + 1];
        } else if (f < 6) {
            int m = 16*(f-2) + row;
            v0 = W2[m*32 + kb]; v1 = W2[m*32 + kb + 1];
        } else {
            int idx = f - 6, mt = idx >> 1, kh = idx & 1;
            int mp = 16*mt + row;
            int om = (mp & 31)*3 + (mp >> 5);
            int k  = 32*kh + kb;
            v0 = W3[om*64 + k]; v1 = W3[om*64 + k + 1];
        }
        wfrag[i] = pk_rtn(v0, v1);
    }
}

// ---- CSR build ---------------------------------------------------------------
__global__ __launch_bounds__(256) void hist_kernel(
    const int* __restrict__ edge_index, int* __restrict__ cnt, int nE)
{
    int e = blockIdx.x * 256 + threadIdx.x;
    if (e < nE) atomicAdd(&cnt[edge_index[nE + e]], 1);
}

__global__ __launch_bounds__(1024) void scanA_kernel(
    const int* __restrict__ cnt, int* __restrict__ rowptr,
    int* __restrict__ csum, int nN)
{
    __shared__ int wsum[16];
    __shared__ int wpre[16];
    int tid = threadIdx.x, lane = tid & 63, wid = tid >> 6;
    int i = blockIdx.x * 1024 + tid;
    int orig = (i < nN) ? cnt[i] : 0;
    int v = orig;
    #pragma unroll
    for (int d = 1; d < 64; d <<= 1) { int o = __shfl_up(v, d); if (lane >= d) v += o; }
    if (lane == 63) wsum[wid] = v;
    __syncthreads();
    if (wid == 0) {
        int s = (lane < 16) ? wsum[lane] : 0;
        #pragma unroll
        for (int d = 1; d < 16; d <<= 1) { int o = __shfl_up(s, d); if (lane >= d) s += o; }
        if (lane < 16) wpre[lane] = s;
    }
    __syncthreads();
    int badd = wid ? wpre[wid - 1] : 0;
    if (i < nN) rowptr[i] = badd + v - orig;
    if (tid == 1023) csum[blockIdx.x] = badd + v;
}

// scanC with scanB folded in: each block computes its own chunk-prefix from
// the raw per-chunk sums (nChunks <= 64) via 64-lane xor-reduce.
__global__ __launch_bounds__(1024) void scanC_kernel(
    const int* __restrict__ csum, int* __restrict__ rowptr, int nN, int nChunks)
{
    __shared__ int sadd[2];
    int tid = threadIdx.x;
    if (tid < 64) {
        int v  = (tid < nChunks) ? csum[tid] : 0;
        int pv = (tid < (int)blockIdx.x) ? v : 0;   // prefix for this block
        int tv = v;                                  // grand total
        #pragma unroll
        for (int d = 1; d < 64; d <<= 1) {
            pv += __shfl_xor(pv, d);
            tv += __shfl_xor(tv, d);
        }
        if (tid == 0) { sadd[0] = pv; sadd[1] = tv; }
    }
    __syncthreads();
    int i = blockIdx.x * 1024 + tid;
    if (i < nN) rowptr[i] += sadd[0];
    if (i == nN - 1) rowptr[nN] = sadd[1];
}

// ---- edge: MFMA MLP, LDS-resident weights, JIT ds_reads ---------------------
// One wave = 16 edges. Transposed: D[m][e] = sum_k W[m][k] act[e][k] + b[m].
// D layout (m89-verified): col(e)=lane&15, row(m)=(lane>>4)*4+r.
// A/B layout: row/col = lane&15, k = 8*(lane>>4)+j (contiguous k, b128-style).
__global__ __launch_bounds__(256) void edge_mfma_kernel(
    const float* __restrict__ edge_attr,
    const float* __restrict__ edge_weight,
    const int* __restrict__ edge_index,
    const int* __restrict__ rowptr,
    int* __restrict__ cursor,
    const unsigned* __restrict__ wfrag,
    const float* __restrict__ ball,
    float* __restrict__ buf, int nE)
{
    __shared__ __align__(16) uint4 swf[1152];   // 18KB: 18 frags x 64 lanes
    __shared__ __align__(16) float sball[192];
    int tid = threadIdx.x;
    {
        const uint4* g4 = reinterpret_cast<const uint4*>(wfrag);
        for (int i = tid; i < 1152; i += 256) swf[i] = g4[i];
        if (tid < 192) sball[tid] = ball[tid];
    }
    __syncthreads();

    int lane = tid & 63;
    int wid  = (blockIdx.x << 2) + (tid >> 6);
    int nW   = gridDim.x << 2;
    int T    = (nE + 15) >> 4;

    int q = lane >> 4, ecol = lane & 15;
    bool hiq = lane >= 32;
    int sl = ecol + ((lane & 16) << 1);
    int sh = sl + 16;

    const uint4*  wl  = &swf[lane];                              // frag f at wl[f*64]
    const float4* bl4 = reinterpret_cast<const float4*>(sball);  // biases

    unsigned* bufu = reinterpret_cast<unsigned*>(buf);

    // prefetch first tile (incl. dst node and its rowptr)
    int tile = wid;
    float4 pA = make_float4(0,0,0,0), pB = pA; float pew = 0.f;
    int pd = 0, prp = 0;
    if (tile < T) {
        int e = tile*16 + ecol; if (e >= nE) e = nE - 1;
        const float* eap = edge_attr + (size_t)e*32 + q*8;
        pA = *reinterpret_cast<const float4*>(eap);
        pB = *reinterpret_cast<const float4*>(eap + 4);
        pew = edge_weight[e];
        if (lane < 16) { pd = edge_index[nE + e]; prp = rowptr[pd]; }
    }

    for (; tile < T; tile += nW) {
        float4 cA = pA, cB = pB; float ew = pew; int d = pd, rp = prp;
        bool ev = (tile*16 + ecol) < nE;

        // opaque zero: defeats LICM on the LDS weight/bias reads below, so
        // they stay JIT ds_reads instead of being hoisted into ~120 VGPRs.
        int ob = 0;
        asm volatile("" : "+v"(ob));

        // slot atomic first: ~300cy L2 latency overlaps all 3 MFMA layers.
        int slot = 0;
        if (lane < 16 && ev) slot = rp + atomicAdd(&cursor[d], 1);
        int slotAll = __shfl(slot, ecol);

        // prefetch next tile
        int nt = tile + nW;
        if (nt < T) {
            int e = nt*16 + ecol; if (e >= nE) e = nE - 1;
            const float* eap = edge_attr + (size_t)e*32 + q*8;
            pA = *reinterpret_cast<const float4*>(eap);
            pB = *reinterpret_cast<const float4*>(eap + 4);
            pew = edge_weight[e];
            if (lane < 16) { pd = edge_index[nE + e]; prp = rowptr[pd]; }
        }

        // B_ea: col=edge, k=8q+j
        U8 bea;
        bea.u[0] = h2bits(pk(cA.x, cA.y));
        bea.u[1] = h2bits(pk(cA.z, cA.w));
        bea.u[2] = h2bits(pk(cB.x, cB.y));
        bea.u[3] = h2bits(pk(cB.z, cB.w));

        // ---- layer 1: h1T(32xE) = silu(W1 @ eaT + b1) ----
        unsigned w1w[4];
        #pragma unroll
        for (int t = 0; t < 2; ++t) {
            U8 wf_; wf_.q = wl[t*64 + ob];
            C4 c; c.f = bl4[4*t + q + ob];
            f32x4 acc = c.v;
            acc = __builtin_amdgcn_mfma_f32_16x16x32_f16(wf_.v, bea.v, acc, 0, 0, 0);
            w1w[2*t]   = h2bits(pk(fast_silu(acc[0]), fast_silu(acc[1])));
            w1w[2*t+1] = h2bits(pk(fast_silu(acc[2]), fast_silu(acc[3])));
        }

        // transpose D->B
        U8 bh1;
        {
            unsigned t0 = (unsigned)__shfl((int)w1w[0], sl), t2 = (unsigned)__shfl((int)w1w[2], sl);
            bh1.u[0] = hiq ? t2 : t0;
            unsigned t1 = (unsigned)__shfl((int)w1w[1], sl), t3 = (unsigned)__shfl((int)w1w[3], sl);
            bh1.u[1] = hiq ? t3 : t1;
            t0 = (unsigned)__shfl((int)w1w[0], sh); t2 = (unsigned)__shfl((int)w1w[2], sh);
            bh1.u[2] = hiq ? t2 : t0;
            t1 = (unsigned)__shfl((int)w1w[1], sh); t3 = (unsigned)__shfl((int)w1w[3], sh);
            bh1.u[3] = hiq ? t3 : t1;
        }

        // ---- layer 2: h2T(64xE) = silu(W2 @ h1T + b2) ----
        unsigned w2w[8];
        #pragma unroll
        for (int t = 0; t < 4; ++t) {
            U8 wf_; wf_.q = wl[(2+t)*64 + ob];
            C4 c; c.f = bl4[8 + 4*t + q + ob];
            f32x4 acc = c.v;
            acc = __builtin_amdgcn_mfma_f32_16x16x32_f16(wf_.v, bh1.v, acc, 0, 0, 0);
            w2w[2*t]   = h2bits(pk(fast_silu(acc[0]), fast_silu(acc[1])));
            w2w[2*t+1] = h2bits(pk(fast_silu(acc[2]), fast_silu(acc[3])));
        }

        // transpose -> two B-frags (k-halves of 64)
        U8 b3f[2];
        #pragma unroll
        for (int h = 0; h < 2; ++h) {
            unsigned ta = (unsigned)__shfl((int)w2w[4*h],   sl), tb = (unsigned)__shfl((int)w2w[4*h+2], sl);
            b3f[h].u[0] = hiq ? tb : ta;
            unsigned tc = (unsigned)__shfl((int)w2w[4*h+1], sl), td = (unsigned)__shfl((int)w2w[4*h+3], sl);
            b3f[h].u[1] = hiq ? td : tc;
            ta = (unsigned)__shfl((int)w2w[4*h],   sh); tb = (unsigned)__shfl((int)w2w[4*h+2], sh);
            b3f[h].u[2] = hiq ? tb : ta;
            tc = (unsigned)__shfl((int)w2w[4*h+1], sh); td = (unsigned)__shfl((int)w2w[4*h+3], sh);
            b3f[h].u[3] = hiq ? td : tc;
        }

        float Cc = (ew < 5.0f) ? 0.5f * (__cosf(ew * 0.6283185307179586f) + 1.0f) : 0.0f;

        // ---- layer 3: out(96xE) = silu(W3p @ h2T + b3p) * Cc ----
        size_t sb = (size_t)slotAll * 48 + 2*q;
        #pragma unroll
        for (int mt = 0; mt < 6; ++mt) {
            U8 wa, wb;
            wa.q = wl[(6+2*mt)*64 + ob];
            wb.q = wl[(7+2*mt)*64 + ob];
            C4 c; c.f = bl4[24 + 4*mt + q + ob];
            f32x4 acc = c.v;
            acc = __builtin_amdgcn_mfma_f32_16x16x32_f16(wa.v, b3f[0].v, acc, 0, 0, 0);
            acc = __builtin_amdgcn_mfma_f32_16x16x32_f16(wb.v, b3f[1].v, acc, 0, 0, 0);
            unsigned p0 = h2bits(pk(fast_silu(acc[0])*Cc, fast_silu(acc[1])*Cc));
            unsigned p1 = h2bits(pk(fast_silu(acc[2])*Cc, fast_silu(acc[3])*Cc));
            if (ev) *reinterpret_cast<uint2*>(bufu + sb + 8*mt) = make_uint2(p0, p1);
        }
    }
}

// ---- node kernel v2: f16 dot2 comp_linear (unchanged from R10) --------------
__device__ __forceinline__ void comp_linear2(
    const unsigned* __restrict__ sW, const unsigned* __restrict__ cbu,
    int u, int call, float& Il, float* a, float* s)
{
    const uint4* w4 = reinterpret_cast<const uint4*>(sW) + call*512 + u;
    const uint4* c4 = reinterpret_cast<const uint4*>(cbu);
    Il = 0.f; a[0]=a[1]=a[2]=0.f;
    s[0]=s[1]=s[2]=s[3]=s[4]=s[5]=0.f;
    #pragma unroll
    for (int kp2 = 0; kp2 < 8; ++kp2) {
        uint4 r0 = c4[kp2*5+0], r1 = c4[kp2*5+1], r2 = c4[kp2*5+2],
              r3 = c4[kp2*5+3], r4 = c4[kp2*5+4];
        uint4 w0 = w4[(2*kp2)*32], w1 = w4[(2*kp2+1)*32];
        Il   = dot2(as_h2(r0.x), as_h2(w0.x), Il);
        a[0] = dot2(as_h2(r0.y), as_h2(w0.y), a[0]);
        a[1] = dot2(as_h2(r0.z), as_h2(w0.y), a[1]);
        a[2] = dot2(as_h2(r0.w), as_h2(w0.y), a[2]);
        s[0] = dot2(as_h2(r1.x), as_h2(w0.z), s[0]);
        s[1] = dot2(as_h2(r1.y), as_h2(w0.z), s[1]);
        s[2] = dot2(as_h2(r1.z), as_h2(w0.z), s[2]);
        s[3] = dot2(as_h2(r1.w), as_h2(w0.z), s[3]);
        s[4] = dot2(as_h2(r2.x), as_h2(w0.z), s[4]);
        s[5] = dot2(as_h2(r2.y), as_h2(w0.z), s[5]);
        Il   = dot2(as_h2(r2.z), as_h2(w1.x), Il);
        a[0] = dot2(as_h2(r2.w), as_h2(w1.y), a[0]);
        a[1] = dot2(as_h2(r3.x), as_h2(w1.y), a[1]);
        a[2] = dot2(as_h2(r3.y), as_h2(w1.y), a[2]);
        s[0] = dot2(as_h2(r3.z), as_h2(w1.z), s[0]);
        s[1] = dot2(as_h2(r3.w), as_h2(w1.z), s[1]);
        s[2] = dot2(as_h2(r4.x), as_h2(w1.z), s[2]);
        s[3] = dot2(as_h2(r4.y), as_h2(w1.z), s[3]);
        s[4] = dot2(as_h2(r4.z), as_h2(w1.z), s[4]);
        s[5] = dot2(as_h2(r4.w), as_h2(w1.z), s[5]);
    }
}

__device__ __forceinline__ void compose(float Il, const float* a, const float* s, float (&T)[3][3])
{
    T[0][0] =  Il  + s[0]; T[0][1] =  a[0] + s[1]; T[0][2] =  a[1] + s[2];
    T[1][0] = -a[0] + s[1]; T[1][1] =  Il  + s[3]; T[1][2] =  a[2] + s[4];
    T[2][0] = -a[1] + s[2]; T[2][1] = -a[2] + s[4]; T[2][2] =  Il  + s[5];
}

__global__ __launch_bounds__(256) void node_kernel(
    const float* __restrict__ X,
    const unsigned* __restrict__ whn,
    const int* __restrict__ rowptr,
    const float* __restrict__ buf,
    float* __restrict__ out, int nN)
{
    __shared__ __align__(16) unsigned sW[4096];     // 16KB f16 weights
    __shared__ __align__(16) _Float16 sC[8][320];   // 5KB cb (f16)

    int tid = threadIdx.x;
    {
        const uint4* g4 = reinterpret_cast<const uint4*>(whn);
        uint4* s4 = reinterpret_cast<uint4*>(sW);
        #pragma unroll
        for (int i = 0; i < 4; ++i) s4[tid + 256*i] = g4[tid + 256*i];
    }

    int ln = tid >> 5, u = tid & 31;
    int n  = blockIdx.x * 8 + ln;
    if (n >= nN) n = nN - 1;
    const unsigned* cbu = reinterpret_cast<const unsigned*>(&sC[ln][0]);
    _Float16* cw = &sC[ln][(u >> 1)*20 + (u & 1)];

    int r0 = rowptr[n], r1 = rowptr[n + 1];
    float sIv = 0.f, sAv = 0.f, sSv = 0.f;
    const _Float16* bp = reinterpret_cast<const _Float16*>(buf) + (size_t)r0 * 96 + u;
    for (int i = r0; i < r1; ++i, bp += 96) {
        sIv += (float)bp[0];    // I plane
        sAv += (float)bp[32];   // A plane
        sSv += (float)bp[64];   // S plane
    }

    const float* xp = X + (size_t)n * 288 + u;
    float x[3][3];
    float nrm = 1.0f;
    #pragma unroll
    for (int i = 0; i < 3; ++i)
        #pragma unroll
        for (int j = 0; j < 3; ++j) {
            float v = xp[(i*3 + j) * 32];
            x[i][j] = v; nrm += v * v;
        }
    float inv = 1.0f / nrm;
    #pragma unroll
    for (int i = 0; i < 3; ++i)
        #pragma unroll
        for (int j = 0; j < 3; ++j) x[i][j] *= inv;

    float tI = (x[0][0] + x[1][1] + x[2][2]) * (1.0f/3.0f);
    cw[0]  = (_Float16)tI;
    cw[2]  = (_Float16)(0.5f * (x[0][1] - x[1][0]));
    cw[4]  = (_Float16)(0.5f * (x[0][2] - x[2][0]));
    cw[6]  = (_Float16)(0.5f * (x[1][2] - x[2][1]));
    cw[8]  = (_Float16)(x[0][0] - tI);
    cw[10] = (_Float16)(0.5f * (x[0][1] + x[1][0]));
    cw[12] = (_Float16)(0.5f * (x[0][2] + x[2][0]));
    cw[14] = (_Float16)(x[1][1] - tI);
    cw[16] = (_Float16)(0.5f * (x[1][2] + x[2][1]));
    cw[18] = (_Float16)(x[2][2] - tI);
    __syncthreads();   // sW staging + cb publish

    float Il, a[3], s[6];
    comp_linear2(sW, cbu, u, 0, Il, a, s);

    float Ym[3][3], Gm[3][3];
    compose(Il, a, s, Ym);
    float am[3] = {a[0]*sAv, a[1]*sAv, a[2]*sAv};
    float sm[6] = {s[0]*sSv, s[1]*sSv, s[2]*sSv, s[3]*sSv, s[4]*sSv, s[5]*sSv};
    compose(Il * sIv, am, sm, Gm);

    float M[3][3]; float np1 = 1.0f;
    #pragma unroll
    for (int i = 0; i < 3; ++i)
        #pragma unroll
        for (int l = 0; l < 3; ++l) {
            float v = 0.f;
            #pragma unroll
            for (int j = 0; j < 3; ++j) v += Ym[i][j]*Gm[j][l] + Gm[i][j]*Ym[j][l];
            M[i][l] = v; np1 += v * v;
        }
    float rinv = 1.0f / np1;
    float tI2 = (M[0][0] + M[1][1] + M[2][2]) * (1.0f/3.0f);

    __builtin_amdgcn_wave_barrier();
    cw[0]  = (_Float16)(tI2 * rinv);
    cw[2]  = (_Float16)(0.5f * (M[0][1] - M[1][0]) * rinv);
    cw[4]  = (_Float16)(0.5f * (M[0][2] - M[2][0]) * rinv);
    cw[6]  = (_Float16)(0.5f * (M[1][2] - M[2][1]) * rinv);
    cw[8]  = (_Float16)((M[0][0] - tI2) * rinv);
    cw[10] = (_Float16)(0.5f * (M[0][1] + M[1][0]) * rinv);
    cw[12] = (_Float16)(0.5f * (M[0][2] + M[2][0]) * rinv);
    cw[14] = (_Float16)((M[1][1] - tI2) * rinv);
    cw[16] = (_Float16)(0.5f * (M[1][2] + M[2][1]) * rinv);
    cw[18] = (_Float16)((M[2][2] - tI2) * rinv);
    __builtin_amdgcn_wave_barrier();

    comp_linear2(sW, cbu, u, 1, Il, a, s);
    float D[3][3];
    compose(Il, a, s, D);

    float* op = out + (size_t)n * 288 + u;
    #pragma unroll
    for (int i = 0; i < 3; ++i)
        #pragma unroll
        for (int l = 0; l < 3; ++l) {
            float v = x[i][l] + D[i][l];
            #pragma unroll
            for (int j = 0; j < 3; ++j) v += D[i][j] * D[j][l];
            op[(i*3 + l) * 32] = v;
        }
}

extern "C" void kernel_launch(void* const* d_in, const int* in_sizes, int n_in,
                              void* d_out, int out_size, void* d_ws, size_t ws_size,
                              hipStream_t stream) {
    const float* X   = (const float*)d_in[0];
    const int*   ei  = (const int*)d_in[1];
    const float* ew  = (const float*)d_in[2];
    const float* ea  = (const float*)d_in[3];
    const float* W1  = (const float*)d_in[4];
    const float* b1  = (const float*)d_in[5];
    const float* W2  = (const float*)d_in[6];
    const float* b2  = (const float*)d_in[7];
    const float* W3  = (const float*)d_in[8];
    const float* b3  = (const float*)d_in[9];
    const float* Wt  = (const float*)d_in[10];

    int nE = in_sizes[2];          // 400000
    int nN = in_sizes[0] / 288;    // 50000
    int nChunks = (nN + 1023) / 1024;

    float* ws       = (float*)d_ws;
    unsigned* whn   = (unsigned*)ws;             // 4096 u32 (16KB), region padded to 8192 f
    float* ball     = ws + 8192;                 // 192 floats (pad to 256)
    unsigned* wfrag = (unsigned*)(ws + 8448);    // 4608 u32 MFMA weight frags
    float* buf      = ws + 8448 + 4608;          // nE*48 floats (= nE*96 halves)
    size_t buf_f    = (size_t)nE * 48;
    int* ib     = (int*)(buf + buf_f);
    int* cntA   = ib;                 // nN
    int* cursor = ib + nN;            // nN  (contiguous with cntA -> zeroed together)
    int* rowptr = ib + 2 * nN;        // nN+1
    int* csum   = ib + 3 * nN + 1;    // nChunks (<=64)

    int zBlocks = (2 * nN + 255) / 256;          // covers zeroing + all prep work
    prep_kernel<<<zBlocks, 256, 0, stream>>>(
        Wt, W1, b1, W2, b2, W3, b3, whn, ball, wfrag, cntA, 2 * nN);
    hist_kernel<<<(nE + 255) / 256, 256, 0, stream>>>(ei, cntA, nE);
    scanA_kernel<<<nChunks, 1024, 0, stream>>>(cntA, rowptr, csum, nN);
    scanC_kernel<<<nChunks, 1024, 0, stream>>>(csum, rowptr, nN, nChunks);
    edge_mfma_kernel<<<1536, 256, 0, stream>>>(
        ea, ew, ei, rowptr, cursor, wfrag, ball, buf, nE);
    node_kernel<<<(nN + 7) / 8, 256, 0, stream>>>(
        X, whn, rowptr, buf, (float*)d_out, nN);
}